// Round 5
// baseline (263.214 us; speedup 1.0000x reference)
//
#include <hip/hip_runtime.h>
#include <hip/hip_bf16.h>

typedef __attribute__((ext_vector_type(8))) short short8;
typedef __attribute__((ext_vector_type(4))) float floatx4;
typedef __attribute__((ext_vector_type(16))) float floatx16;
typedef unsigned short ushortt;

#define LOG2E 1.4426950408889634f

__device__ __forceinline__ float fast_exp2(float x) {
    return __builtin_amdgcn_exp2f(x);      // v_exp_f32, 1 instr (libm exp2f is ~20)
}
__device__ __forceinline__ ushortt f2bf(float f) {
    unsigned int u = __float_as_uint(f);
    u += 0x7fffu + ((u >> 16) & 1u);
    return (ushortt)(u >> 16);
}
__device__ __forceinline__ unsigned int f2bf_pk(float a, float b) {
    float2 t; t.x = a; t.y = b;
    __hip_bfloat162 h = __float22bfloat162_rn(t);
    return *reinterpret_cast<unsigned int*>(&h);
}
__device__ __forceinline__ float bf2f(ushortt h) {
    return __uint_as_float(((unsigned int)h) << 16);
}

__device__ __forceinline__ float block_sum(float v, float* red) {
    #pragma unroll
    for (int off = 32; off > 0; off >>= 1) v += __shfl_down(v, off);
    int wid = threadIdx.x >> 6, ln = threadIdx.x & 63;
    __syncthreads();
    if (ln == 0) red[wid] = v;
    __syncthreads();
    return red[0] + red[1] + red[2] + red[3];
}

// ---------------------------------------------------------------------------
// sigma = ||W @ normalize(W^T u)|| + fused bf16 weight conversion (per block)
// ---------------------------------------------------------------------------
__global__ __launch_bounds__(256) void sigma_kernel(
    const float* __restrict__ Wf, const float* __restrict__ uf,
    const float* __restrict__ Wg, const float* __restrict__ ug,
    const float* __restrict__ Wh, const float* __restrict__ uh,
    const float* __restrict__ Wv, const float* __restrict__ uv,
    float* __restrict__ sig, ushortt* __restrict__ wqkv, ushortt* __restrict__ wvb) {
    __shared__ float tv[512];
    __shared__ float tvp[256];
    __shared__ float red[4];
    __shared__ float sbc;
    const int mat = blockIdx.x, tid = threadIdx.x;
    const int wave = tid >> 6, lane = tid & 63;

    if (mat < 3) {
        const float* W = (mat == 0) ? Wf : ((mat == 1) ? Wg : Wh);
        const float* u = (mat == 0) ? uf : ((mat == 1) ? ug : uh);
        for (int c = tid; c < 512; c += 256) {
            float s0 = 0.f;
            #pragma unroll 8
            for (int r = 0; r < 64; ++r) s0 += W[r * 512 + c] * u[r];
            tv[c] = s0;
        }
        __syncthreads();
        float p = tv[tid] * tv[tid] + tv[tid + 256] * tv[tid + 256];
        float nt2 = block_sum(p, red);
        float nt = fmaxf(sqrtf(nt2), 1e-12f);
        float z2p = 0.f;
        for (int rr = wave; rr < 64; rr += 4) {
            float part = 0.f;
            #pragma unroll
            for (int j = 0; j < 8; ++j) part += W[rr * 512 + lane + 64 * j] * tv[lane + 64 * j];
            #pragma unroll
            for (int off = 32; off > 0; off >>= 1) part += __shfl_xor(part, off);
            z2p += part * part;
        }
        __syncthreads();
        if (lane == 0) red[wave] = z2p;
        __syncthreads();
        if (tid == 0) {
            float sv = sqrtf(red[0] + red[1] + red[2] + red[3]) / nt;
            sig[mat] = sv;
            sbc = sv;
        }
        __syncthreads();
        float inv = 1.0f / sbc;
        for (int idx = tid; idx < 32768; idx += 256)
            wqkv[mat * 32768 + idx] = f2bf(W[idx] * inv);
    } else {
        const float* W = Wv; const float* u = uv;
        {
            int c = tid & 63, rs = tid >> 6;
            float s0 = 0.f;
            #pragma unroll 8
            for (int r = rs * 128; r < rs * 128 + 128; ++r) s0 += W[r * 64 + c] * u[r];
            tvp[tid] = s0;
        }
        __syncthreads();
        if (tid < 64) tv[tid] = tvp[tid] + tvp[tid + 64] + tvp[tid + 128] + tvp[tid + 192];
        __syncthreads();
        float t = (tid < 64) ? tv[tid] : 0.f;
        float nt2 = block_sum(t * t, red);
        float nt = fmaxf(sqrtf(nt2), 1e-12f);
        float z2p = 0.f;
        for (int rr = wave; rr < 512; rr += 4) {
            float part = W[rr * 64 + lane] * tv[lane];
            #pragma unroll
            for (int off = 32; off > 0; off >>= 1) part += __shfl_xor(part, off);
            z2p += part * part;
        }
        __syncthreads();
        if (lane == 0) red[wave] = z2p;
        __syncthreads();
        if (tid == 0) {
            float sv = sqrtf(red[0] + red[1] + red[2] + red[3]) / nt;
            sig[3] = sv;
            sbc = sv;
        }
        __syncthreads();
        float inv = 1.0f / sbc;
        for (int idx = tid; idx < 32768; idx += 256)
            wvb[idx] = f2bf(W[idx] * inv);
    }
}

// ---------------------------------------------------------------------------
// QKV projection, 32-pixel tiles. XOR-swizzled LDS: row n (32 rows) x 8
// 16B-chunks; chunk c stored at c^(row&7) -> all b128, conflict-free.
// Q stored pre-scaled by LOG2E. V stored transposed Vt[b][d][n].
// ---------------------------------------------------------------------------
__global__ __launch_bounds__(256) void qkv_kernel(
    const float* __restrict__ x, const ushortt* __restrict__ wqkv,
    const float* __restrict__ bfv, const float* __restrict__ bgv,
    const float* __restrict__ bhv,
    ushortt* __restrict__ Qb, ushortt* __restrict__ Kb, ushortt* __restrict__ Vt) {
    __shared__ unsigned int xs[1120];          // main loop: 32 rows x 32 dwords
    const int tid = threadIdx.x;
    const int n0 = blockIdx.x * 32, b = blockIdx.y;
    const int lane = tid & 63, w = tid >> 6;
    const int strip = w & 1, ksel = w >> 1;
    const int q = lane >> 4, l15 = lane & 15;
    const int sn = tid & 31, sg = tid >> 5;    // staging: pixel sn, chunk sg

    floatx4 acc[6];
    #pragma unroll
    for (int kt = 0; kt < 6; ++kt) acc[kt] = (floatx4){0.f, 0.f, 0.f, 0.f};

    const float* xb = x + ((size_t)b * 512) * 4096 + n0 + sn;
    float2 pre[4];
    #pragma unroll
    for (int i = 0; i < 4; ++i) {
        int c = sg * 8 + 2 * i;
        pre[i].x = xb[(size_t)c * 4096];
        pre[i].y = xb[(size_t)(c + 1) * 4096];
    }

    for (int c0 = 0; c0 < 512; c0 += 64) {
        __syncthreads();
        {
            uint4 pk;
            pk.x = f2bf_pk(pre[0].x, pre[0].y);
            pk.y = f2bf_pk(pre[1].x, pre[1].y);
            pk.z = f2bf_pk(pre[2].x, pre[2].y);
            pk.w = f2bf_pk(pre[3].x, pre[3].y);
            *reinterpret_cast<uint4*>(&xs[sn * 32 + ((sg ^ (sn & 7)) << 2)]) = pk;
        }
        if (c0 + 64 < 512) {
            #pragma unroll
            for (int i = 0; i < 4; ++i) {
                int c = c0 + 64 + sg * 8 + 2 * i;
                pre[i].x = xb[(size_t)c * 4096];
                pre[i].y = xb[(size_t)(c + 1) * 4096];
            }
        }
        __syncthreads();
        const unsigned int* xr = &xs[(16 * strip + l15) * 32];
        #pragma unroll
        for (int kc = 0; kc < 2; ++kc) {
            union { uint4 v; short8 s8; } af;
            af.v = *reinterpret_cast<const uint4*>(&xr[((4 * kc + q) ^ (l15 & 7)) << 2]);
            #pragma unroll
            for (int kt = 0; kt < 6; ++kt) {
                short8 bb = *reinterpret_cast<const short8*>(
                    &wqkv[(size_t)(ksel * 96 + kt * 16 + l15) * 512 + c0 + kc * 32 + q * 8]);
                acc[kt] = __builtin_amdgcn_mfma_f32_16x16x32_bf16(af.s8, bb, acc[kt], 0, 0, 0);
            }
        }
    }

    const int nloc = n0 + 16 * strip + 4 * q;
    if (ksel == 0) {
        #pragma unroll
        for (int kt = 0; kt < 4; ++kt) {       // Q (exp2-domain)
            int k = kt * 16 + l15;
            float bb = bfv[k];
            #pragma unroll
            for (int r = 0; r < 4; ++r)
                Qb[((size_t)b * 4096 + nloc + r) * 64 + k] = f2bf((acc[kt][r] + bb) * LOG2E);
        }
        #pragma unroll
        for (int kt = 4; kt < 6; ++kt) {       // K rows 0..31
            int k = (kt - 4) * 16 + l15;
            float bb = bgv[k];
            #pragma unroll
            for (int r = 0; r < 4; ++r)
                Kb[((size_t)b * 4096 + nloc + r) * 64 + k] = f2bf(acc[kt][r] + bb);
        }
    } else {
        #pragma unroll
        for (int kt = 0; kt < 2; ++kt) {       // K rows 32..63
            int k = 32 + kt * 16 + l15;
            float bb = bgv[k];
            #pragma unroll
            for (int r = 0; r < 4; ++r)
                Kb[((size_t)b * 4096 + nloc + r) * 64 + k] = f2bf(acc[kt][r] + bb);
        }
    }
    __syncthreads();
    if (ksel == 1) {                           // V -> LDS [d][n/2] (stride 17 dwords)
        #pragma unroll
        for (int kt = 2; kt < 6; ++kt) {
            int d = (kt - 2) * 16 + l15;
            float bb = bhv[d];
            int base = d * 17 + 8 * strip + 2 * q;
            xs[base]     = f2bf_pk(acc[kt][0] + bb, acc[kt][1] + bb);
            xs[base + 1] = f2bf_pk(acc[kt][2] + bb, acc[kt][3] + bb);
        }
    }
    __syncthreads();
    {   // coalesced store Vt[b][d][n0..n0+31]
        int d = tid >> 2, sgg = tid & 3;
        uint4 vv;
        vv.x = xs[d * 17 + sgg * 4 + 0]; vv.y = xs[d * 17 + sgg * 4 + 1];
        vv.z = xs[d * 17 + sgg * 4 + 2]; vv.w = xs[d * 17 + sgg * 4 + 3];
        *reinterpret_cast<uint4*>(&Vt[((size_t)b * 64 + d) * 4096 + n0 + sgg * 8]) = vv;
    }
}

// ---------------------------------------------------------------------------
// Flash attention, 32x32x16 MFMA, XOR-swizzled b128 LDS, v_exp_f32 softmax.
// Wave (qh,kh): 32 queries x 32 keys per 64-key tile. Q register-resident
// (exp2-domain). P in-register (shfl C->B transform). kh merged via LDS.
// ---------------------------------------------------------------------------
__global__ __launch_bounds__(256) void attn_kernel(
    const ushortt* __restrict__ Qb, const ushortt* __restrict__ Kb,
    const ushortt* __restrict__ Vt, ushortt* __restrict__ Opart,
    float2* __restrict__ ml, ushortt* __restrict__ Ob, int KB) {
    __shared__ unsigned int smem[4420];
    // staging: KS = smem[0..2048), VS = smem[2048..4096)  (64 rows x 8 chunks, swizzled)
    // merge:   OM = smem[0..4160) (64 x 65 f32), MLm = [4160..4288), MLl = [4288..4416)
    const int tid = threadIdx.x;
    const int n0 = blockIdx.x * 64, b = blockIdx.y, s = blockIdx.z;
    const int lane = tid & 63, w = tid >> 6;
    const int qh = w & 1, kh = w >> 1;
    const int l31 = lane & 31, h = lane >> 5;

    const ushortt* Kg = Kb + (size_t)b * 4096 * 64;
    const ushortt* Vg = Vt + (size_t)b * 64 * 4096;

    short8 bq[4];
    {
        const ushortt* Qg = Qb + ((size_t)b * 4096 + n0 + 32 * qh + l31) * 64;
        #pragma unroll
        for (int kc = 0; kc < 4; ++kc)
            bq[kc] = *reinterpret_cast<const short8*>(Qg + kc * 16 + 8 * h);
    }

    floatx16 ot0 = {}, ot1 = {};
    float m_i = -1e30f, l_i = 0.f;

    const int row = tid >> 2, seg = tid & 3;   // staging roles
    const int kbeg = s * KB, kend = kbeg + KB;

    uint4 ck0, ck1, cv0, cv1;
    {
        int nb = kbeg * 64;
        const ushortt* kp = Kg + (size_t)(nb + row) * 64 + seg * 16;
        ck0 = *reinterpret_cast<const uint4*>(kp);
        ck1 = *reinterpret_cast<const uint4*>(kp + 8);
        const ushortt* vp = Vg + (size_t)row * 4096 + nb + seg * 16;
        cv0 = *reinterpret_cast<const uint4*>(vp);
        cv1 = *reinterpret_cast<const uint4*>(vp + 8);
    }

    const int rsw = row & 7;
    for (int kb = kbeg; kb < kend; ++kb) {
        __syncthreads();
        {   // swizzled b128 staging: chunk c at c^(row&7)
            *reinterpret_cast<uint4*>(&smem[row * 32 + (((2 * seg) ^ rsw) << 2)]) = ck0;
            *reinterpret_cast<uint4*>(&smem[row * 32 + (((2 * seg + 1) ^ rsw) << 2)]) = ck1;
            *reinterpret_cast<uint4*>(&smem[2048 + row * 32 + (((2 * seg) ^ rsw) << 2)]) = cv0;
            *reinterpret_cast<uint4*>(&smem[2048 + row * 32 + (((2 * seg + 1) ^ rsw) << 2)]) = cv1;
        }
        if (kb + 1 < kend) {   // prefetch next tile
            int nb = (kb + 1) * 64;
            const ushortt* kp = Kg + (size_t)(nb + row) * 64 + seg * 16;
            ck0 = *reinterpret_cast<const uint4*>(kp);
            ck1 = *reinterpret_cast<const uint4*>(kp + 8);
            const ushortt* vp = Vg + (size_t)row * 4096 + nb + seg * 16;
            cv0 = *reinterpret_cast<const uint4*>(vp);
            cv1 = *reinterpret_cast<const uint4*>(vp + 8);
        }
        __syncthreads();

        // S^T = K Q'^T  (32 keys x 32 queries), exp2-domain
        floatx16 st = {};
        const unsigned int* kr = &smem[(32 * kh + l31) * 32];
        const int esw = l31 & 7;
        #pragma unroll
        for (int kc = 0; kc < 4; ++kc) {
            union { uint4 v; short8 s8; } af;
            af.v = *reinterpret_cast<const uint4*>(&kr[((2 * kc + h) ^ esw) << 2]);
            st = __builtin_amdgcn_mfma_f32_32x32x16_bf16(af.s8, bq[kc], st, 0, 0, 0);
        }

        // online softmax over this wave's 32 keys for column q=l31
        float mx = st[0];
        #pragma unroll
        for (int r = 1; r < 16; ++r) mx = fmaxf(mx, st[r]);
        mx = fmaxf(mx, __shfl_xor(mx, 32));
        if (__any(mx > m_i)) {
            float mn = fmaxf(m_i, mx);
            float alpha = fast_exp2(m_i - mn);
            m_i = mn;
            l_i *= alpha;
            #pragma unroll
            for (int r = 0; r < 16; ++r) { ot0[r] *= alpha; ot1[r] *= alpha; }
        }
        float p[16], rs = 0.f;
        #pragma unroll
        for (int r = 0; r < 16; ++r) { p[r] = fast_exp2(st[r] - m_i); rs += p[r]; }
        rs += __shfl_xor(rs, 32);
        l_i += rs;

        // P: C-layout -> B-operand frags, in-register
        unsigned int pk[8], sp[8];
        #pragma unroll
        for (int i = 0; i < 8; ++i) pk[i] = f2bf_pk(p[2 * i], p[2 * i + 1]);
        #pragma unroll
        for (int i = 0; i < 8; ++i) sp[i] = (unsigned int)__shfl_xor((int)pk[i], 32);
        union { unsigned int u[4]; short8 s8; } pb0, pb1;
        pb0.u[0] = h ? sp[2] : pk[0]; pb0.u[1] = h ? sp[3] : pk[1];
        pb0.u[2] = h ? pk[2] : sp[0]; pb0.u[3] = h ? pk[3] : sp[1];
        pb1.u[0] = h ? sp[6] : pk[4]; pb1.u[1] = h ? sp[7] : pk[5];
        pb1.u[2] = h ? pk[6] : sp[4]; pb1.u[3] = h ? pk[7] : sp[5];

        // O^T += V^T P  (2 d-strips x 2 key-chunks)
        const unsigned int* vr0 = &smem[2048 + l31 * 32];
        const unsigned int* vr1 = &smem[2048 + (32 + l31) * 32];
        #pragma unroll
        for (int c = 0; c < 2; ++c) {
            union { uint4 v; short8 s8; } af;
            af.v = *reinterpret_cast<const uint4*>(&vr0[((4 * kh + 2 * c + h) ^ esw) << 2]);
            ot0 = __builtin_amdgcn_mfma_f32_32x32x16_bf16(af.s8, c ? pb1.s8 : pb0.s8, ot0, 0, 0, 0);
            af.v = *reinterpret_cast<const uint4*>(&vr1[((4 * kh + 2 * c + h) ^ esw) << 2]);
            ot1 = __builtin_amdgcn_mfma_f32_32x32x16_bf16(af.s8, c ? pb1.s8 : pb0.s8, ot1, 0, 0, 0);
        }
    }

    // ---- merge kh halves ----
    __syncthreads();
    if (h == 0) {
        smem[4160 + w * 32 + l31] = __float_as_uint(m_i);
        smem[4288 + w * 32 + l31] = __float_as_uint(l_i);
    }
    __syncthreads();
    int pw = 2 * (1 - kh) + qh;
    float m2 = __uint_as_float(smem[4160 + pw * 32 + l31]);
    float l2 = __uint_as_float(smem[4288 + pw * 32 + l31]);
    float mstar = fmaxf(m_i, m2);
    float wself = fast_exp2(m_i - mstar);
    float w2 = fast_exp2(m2 - mstar);
    float lm = wself * l_i + w2 * l2;
    float sc = (gridDim.z == 1) ? (wself / lm) : wself;
    if (gridDim.z > 1 && kh == 0 && h == 0) {
        float2 v; v.x = mstar; v.y = lm;
        ml[((size_t)s * 4 + b) * 4096 + n0 + 32 * qh + l31] = v;
    }
    float* om = reinterpret_cast<float*>(smem);
    if (kh == 0) {
        #pragma unroll
        for (int r = 0; r < 16; ++r) {
            int d0 = (r & 3) + 8 * (r >> 2) + 4 * h;
            om[(32 * qh + l31) * 65 + d0] = sc * ot0[r];
            om[(32 * qh + l31) * 65 + 32 + d0] = sc * ot1[r];
        }
    }
    __syncthreads();
    if (kh == 1) {
        #pragma unroll
        for (int r = 0; r < 16; ++r) {
            int d0 = (r & 3) + 8 * (r >> 2) + 4 * h;
            om[(32 * qh + l31) * 65 + d0] += sc * ot0[r];
            om[(32 * qh + l31) * 65 + 32 + d0] += sc * ot1[r];
        }
    }
    __syncthreads();
    {   // coalesced bf16 store
        int qq = tid >> 2, dsg = tid & 3;
        unsigned int pkk[8];
        #pragma unroll
        for (int j = 0; j < 8; ++j)
            pkk[j] = f2bf_pk(om[qq * 65 + dsg * 16 + 2 * j], om[qq * 65 + dsg * 16 + 2 * j + 1]);
        ushortt* base = (gridDim.z == 1)
            ? (Ob + ((size_t)b * 4096 + n0) * 64)
            : (Opart + (((size_t)s * 4 + b) * 4096 + n0) * 64);
        uint4* d4 = reinterpret_cast<uint4*>(base + (size_t)qq * 64 + dsg * 16);
        uint4 o0; o0.x = pkk[0]; o0.y = pkk[1]; o0.z = pkk[2]; o0.w = pkk[3];
        uint4 o1; o1.x = pkk[4]; o1.y = pkk[5]; o1.z = pkk[6]; o1.w = pkk[7];
        d4[0] = o0; d4[1] = o1;
    }
}

// ---------------------------------------------------------------------------
// Merge KV-split partials (bf16 Opart, exp2-domain m).
// ---------------------------------------------------------------------------
__global__ __launch_bounds__(256) void combine_kernel(
    const ushortt* __restrict__ Opart, const float2* __restrict__ ml,
    ushortt* __restrict__ Ob, int S) {
    const int tid = threadIdx.x;
    const int n0 = blockIdx.x * 64, b = blockIdx.y;
    const int row = n0 + (tid >> 2), dseg = tid & 3;
    float2 mls[4];
    float m = -1e30f;
    for (int s = 0; s < S; ++s) {
        mls[s] = ml[((size_t)s * 4 + b) * 4096 + row];
        m = fmaxf(m, mls[s].x);
    }
    float wgt[4], denom = 0.f;
    for (int s = 0; s < S; ++s) {
        wgt[s] = fast_exp2(mls[s].x - m);
        denom += wgt[s] * mls[s].y;
    }
    float inv = 1.0f / denom;
    float acc[16];
    #pragma unroll
    for (int j = 0; j < 16; ++j) acc[j] = 0.f;
    for (int s = 0; s < S; ++s) {
        const uint4* op = reinterpret_cast<const uint4*>(
            Opart + (((size_t)s * 4 + b) * 4096 + row) * 64 + dseg * 16);
        union { uint4 v; ushortt hh[8]; } u0, u1;
        u0.v = op[0]; u1.v = op[1];
        float ww = wgt[s];
        #pragma unroll
        for (int j = 0; j < 8; ++j) {
            acc[j] += ww * bf2f(u0.hh[j]);
            acc[8 + j] += ww * bf2f(u1.hh[j]);
        }
    }
    union { uint4 u[2]; unsigned int ww[8]; } pkv;
    #pragma unroll
    for (int j = 0; j < 8; ++j) pkv.ww[j] = f2bf_pk(acc[2 * j] * inv, acc[2 * j + 1] * inv);
    uint4* dst = reinterpret_cast<uint4*>(Ob + ((size_t)b * 4096 + row) * 64 + dseg * 16);
    dst[0] = pkv.u[0]; dst[1] = pkv.u[1];
}

// ---------------------------------------------------------------------------
// out = gamma*(Wv_sn O + bv) + x
// ---------------------------------------------------------------------------
__global__ __launch_bounds__(256) void proj_kernel(
    const ushortt* __restrict__ Ob, const ushortt* __restrict__ wvb,
    const float* __restrict__ bv, const float* __restrict__ gamma,
    const float* __restrict__ x, float* __restrict__ out) {
    const int tid = threadIdx.x;
    const int n0 = blockIdx.y * 64, c0 = blockIdx.x * 64, b = blockIdx.z;
    const int w = tid >> 6, lane = tid & 63, q = lane >> 4, l15 = lane & 15;

    short8 a0 = *reinterpret_cast<const short8*>(&wvb[(size_t)(c0 + 16 * w + l15) * 64 + q * 8]);
    short8 a1 = *reinterpret_cast<const short8*>(&wvb[(size_t)(c0 + 16 * w + l15) * 64 + 32 + q * 8]);
    floatx4 acc[4];
    #pragma unroll
    for (int t = 0; t < 4; ++t) acc[t] = (floatx4){0.f, 0.f, 0.f, 0.f};
    #pragma unroll
    for (int t = 0; t < 4; ++t) {
        const ushortt* ob = Ob + ((size_t)b * 4096 + n0 + 16 * t + l15) * 64;
        short8 b0 = *reinterpret_cast<const short8*>(ob + q * 8);
        short8 b1 = *reinterpret_cast<const short8*>(ob + 32 + q * 8);
        acc[t] = __builtin_amdgcn_mfma_f32_16x16x32_bf16(a0, b0, acc[t], 0, 0, 0);
        acc[t] = __builtin_amdgcn_mfma_f32_16x16x32_bf16(a1, b1, acc[t], 0, 0, 0);
    }
    float gm = gamma[0];
    #pragma unroll
    for (int t = 0; t < 4; ++t) {
        #pragma unroll
        for (int r = 0; r < 4; ++r) {
            int c = c0 + 16 * w + 4 * q + r;
            int n = n0 + 16 * t + l15;
            size_t idx = ((size_t)(b * 512 + c)) * 4096 + n;
            out[idx] = gm * (acc[t][r] + bv[c]) + x[idx];
        }
    }
}

// ---------------------------------------------------------------------------
extern "C" void kernel_launch(void* const* d_in, const int* in_sizes, int n_in,
                              void* d_out, int out_size, void* d_ws, size_t ws_size,
                              hipStream_t stream) {
    const float* x   = (const float*)d_in[0];
    const float* Wf  = (const float*)d_in[1];
    const float* bf_ = (const float*)d_in[2];
    const float* Wg  = (const float*)d_in[3];
    const float* bg_ = (const float*)d_in[4];
    const float* Wh  = (const float*)d_in[5];
    const float* bh_ = (const float*)d_in[6];
    const float* Wv  = (const float*)d_in[7];
    const float* bv_ = (const float*)d_in[8];
    const float* uf  = (const float*)d_in[9];
    const float* ug  = (const float*)d_in[10];
    const float* uh  = (const float*)d_in[11];
    const float* uv  = (const float*)d_in[12];
    const float* gm  = (const float*)d_in[13];
    float* out = (float*)d_out;

    char* ws = (char*)d_ws;
    float*   sig   = (float*)ws;                         // 256 B
    ushortt* wqkv  = (ushortt*)(ws + 256);               // 196608
    ushortt* wvb   = (ushortt*)(ws + 196864);            // 65536
    ushortt* Qb    = (ushortt*)(ws + 262400);            // 2 MB
    ushortt* Kb    = (ushortt*)(ws + 2359552);           // 2 MB
    ushortt* Vt    = (ushortt*)(ws + 4456704);           // 2 MB  [b][d][n]
    ushortt* Ob    = (ushortt*)(ws + 6553856);           // 2 MB
    float2*  ml    = (float2*)(ws + 8651008);            // 512 KB (S=4)
    ushortt* Opart = (ushortt*)(ws + 9175296);           // 8 MB bf16 (S=4)

    int S = (ws_size >= (size_t)17563904) ? 4 : 1;

    sigma_kernel<<<4, 256, 0, stream>>>(Wf, uf, Wg, ug, Wh, uh, Wv, uv, sig, wqkv, wvb);
    qkv_kernel<<<dim3(128, 4), 256, 0, stream>>>(x, wqkv, bf_, bg_, bh_, Qb, Kb, Vt);
    attn_kernel<<<dim3(64, 4, S), 256, 0, stream>>>(Qb, Kb, Vt, Opart, ml, Ob, 64 / S);
    if (S > 1) combine_kernel<<<dim3(64, 4), 256, 0, stream>>>(Opart, ml, Ob, S);
    proj_kernel<<<dim3(8, 64, 4), 256, 0, stream>>>(Ob, wvb, bv_, gm, x, out);
}

// Round 6
// 206.942 us; speedup vs baseline: 1.2719x; 1.2719x over previous
//
#include <hip/hip_runtime.h>
#include <hip/hip_bf16.h>

typedef __attribute__((ext_vector_type(8))) short short8;
typedef __attribute__((ext_vector_type(4))) float floatx4;
typedef __attribute__((ext_vector_type(16))) float floatx16;
typedef unsigned short ushortt;

#define LOG2E 1.4426950408889634f

__device__ __forceinline__ float fast_exp2(float x) {
    return __builtin_amdgcn_exp2f(x);      // raw v_exp_f32
}
__device__ __forceinline__ ushortt f2bf(float f) {
    unsigned int u = __float_as_uint(f);
    u += 0x7fffu + ((u >> 16) & 1u);
    return (ushortt)(u >> 16);
}
__device__ __forceinline__ unsigned int f2bf_pk(float a, float b) {
    float2 t; t.x = a; t.y = b;
    __hip_bfloat162 h = __float22bfloat162_rn(t);
    return *reinterpret_cast<unsigned int*>(&h);
}
__device__ __forceinline__ float bf2f(ushortt h) {
    return __uint_as_float(((unsigned int)h) << 16);
}

__device__ __forceinline__ float block_sum(float v, float* red) {
    #pragma unroll
    for (int off = 32; off > 0; off >>= 1) v += __shfl_down(v, off);
    int wid = threadIdx.x >> 6, ln = threadIdx.x & 63;
    __syncthreads();
    if (ln == 0) red[wid] = v;
    __syncthreads();
    return red[0] + red[1] + red[2] + red[3];
}

// ---------------------------------------------------------------------------
// sigma = ||W @ normalize(W^T u)||  — phase2 is row-per-thread dots (no
// per-row butterfly chains; single block-level reduction at the end).
// ---------------------------------------------------------------------------
__global__ __launch_bounds__(256) void sigma_kernel(
    const float* __restrict__ Wf, const float* __restrict__ uf,
    const float* __restrict__ Wg, const float* __restrict__ ug,
    const float* __restrict__ Wh, const float* __restrict__ uh,
    const float* __restrict__ Wv, const float* __restrict__ uv,
    float* __restrict__ sig) {
    __shared__ float tv[512];
    __shared__ float tvp[256];
    __shared__ float zpart[256];
    __shared__ float red[4];
    const int mat = blockIdx.x, tid = threadIdx.x;

    if (mat < 3) {  // W: [64][512]
        const float* W = (mat == 0) ? Wf : ((mat == 1) ? Wg : Wh);
        const float* u = (mat == 0) ? uf : ((mat == 1) ? ug : uh);
        // phase 1: tv[c] = sum_r W[r][c] u[r]  (coalesced over c)
        for (int c = tid; c < 512; c += 256) {
            float s0 = 0.f;
            #pragma unroll 8
            for (int r = 0; r < 64; ++r) s0 += W[r * 512 + c] * u[r];
            tv[c] = s0;
        }
        __syncthreads();
        float p = tv[tid] * tv[tid] + tv[tid + 256] * tv[tid + 256];
        float nt2 = block_sum(p, red);
        float nt = fmaxf(sqrtf(nt2), 1e-12f);
        // phase 2: row r = tid&63, quarter qq = tid>>6 (128 cols each)
        {
            int r = tid & 63, qq = tid >> 6;
            const float* Wr = W + r * 512 + qq * 128;
            const float* tq = tv + qq * 128;
            float part = 0.f;
            #pragma unroll 16
            for (int c = 0; c < 128; ++c) part += Wr[c] * tq[c];
            zpart[tid] = part;
        }
        __syncthreads();
        if (tid < 64) {
            float z = zpart[tid] + zpart[tid + 64] + zpart[tid + 128] + zpart[tid + 192];
            z = z * z;
            #pragma unroll
            for (int off = 32; off > 0; off >>= 1) z += __shfl_xor(z, off);
            if (tid == 0) sig[mat] = sqrtf(z) / nt;
        }
    } else {        // Wv: [512][64]
        const float* W = Wv; const float* u = uv;
        {
            int c = tid & 63, rs = tid >> 6;
            float s0 = 0.f;
            #pragma unroll 8
            for (int r = rs * 128; r < rs * 128 + 128; ++r) s0 += W[r * 64 + c] * u[r];
            tvp[tid] = s0;
        }
        __syncthreads();
        if (tid < 64) tv[tid] = tvp[tid] + tvp[tid + 64] + tvp[tid + 128] + tvp[tid + 192];
        __syncthreads();
        float t = (tid < 64) ? tv[tid] : 0.f;
        float nt2 = block_sum(t * t, red);
        float nt = fmaxf(sqrtf(nt2), 1e-12f);
        // phase 2: rows tid and tid+256, full 64-col dot per thread
        {
            const float* w1 = W + (size_t)tid * 64;
            const float* w2 = W + (size_t)(tid + 256) * 64;
            float z1 = 0.f, z2 = 0.f;
            #pragma unroll 8
            for (int c = 0; c < 64; ++c) {
                float tc = tv[c];
                z1 += w1[c] * tc;
                z2 += w2[c] * tc;
            }
            float zp = z1 * z1 + z2 * z2;
            float z2t = block_sum(zp, red);
            if (tid == 0) sig[3] = sqrtf(z2t) / nt;
        }
    }
}

// ---------------------------------------------------------------------------
// Pre-scale weights by 1/sigma, convert to bf16 (grid 512 — fully parallel).
// ---------------------------------------------------------------------------
__global__ __launch_bounds__(256) void prep_w_kernel(
    const float* __restrict__ Wf, const float* __restrict__ Wg,
    const float* __restrict__ Wh, const float* __restrict__ Wv,
    const float* __restrict__ sig,
    ushortt* __restrict__ wqkv, ushortt* __restrict__ wvb) {
    int idx = blockIdx.x * 256 + threadIdx.x;
    if (idx < 98304) {
        int k = idx >> 9, c = idx & 511;
        int which = k >> 6;
        const float* W = (which == 0) ? Wf : ((which == 1) ? Wg : Wh);
        float inv = 1.0f / sig[which];
        wqkv[idx] = f2bf(W[(k & 63) * 512 + c] * inv);
    } else {
        int o = idx - 98304;
        wvb[o] = f2bf(Wv[o] / sig[3]);
    }
}

// ---------------------------------------------------------------------------
// QKV projection, 32-pixel tiles. XOR-swizzled LDS (all b128, conflict-free).
// Q stored pre-scaled by LOG2E. V stored transposed Vt[b][d][n].
// ---------------------------------------------------------------------------
__global__ __launch_bounds__(256, 4) void qkv_kernel(
    const float* __restrict__ x, const ushortt* __restrict__ wqkv,
    const float* __restrict__ bfv, const float* __restrict__ bgv,
    const float* __restrict__ bhv,
    ushortt* __restrict__ Qb, ushortt* __restrict__ Kb, ushortt* __restrict__ Vt) {
    __shared__ unsigned int xs[1120];          // main loop: 32 rows x 32 dwords
    const int tid = threadIdx.x;
    const int n0 = blockIdx.x * 32, b = blockIdx.y;
    const int lane = tid & 63, w = tid >> 6;
    const int strip = w & 1, ksel = w >> 1;
    const int q = lane >> 4, l15 = lane & 15;
    const int sn = tid & 31, sg = tid >> 5;    // staging: pixel sn, chunk sg

    floatx4 acc[6];
    #pragma unroll
    for (int kt = 0; kt < 6; ++kt) acc[kt] = (floatx4){0.f, 0.f, 0.f, 0.f};

    const float* xb = x + ((size_t)b * 512) * 4096 + n0 + sn;
    float2 pre[4];
    #pragma unroll
    for (int i = 0; i < 4; ++i) {
        int c = sg * 8 + 2 * i;
        pre[i].x = xb[(size_t)c * 4096];
        pre[i].y = xb[(size_t)(c + 1) * 4096];
    }

    for (int c0 = 0; c0 < 512; c0 += 64) {
        __syncthreads();
        {
            uint4 pk;
            pk.x = f2bf_pk(pre[0].x, pre[0].y);
            pk.y = f2bf_pk(pre[1].x, pre[1].y);
            pk.z = f2bf_pk(pre[2].x, pre[2].y);
            pk.w = f2bf_pk(pre[3].x, pre[3].y);
            *reinterpret_cast<uint4*>(&xs[sn * 32 + ((sg ^ (sn & 7)) << 2)]) = pk;
        }
        if (c0 + 64 < 512) {
            #pragma unroll
            for (int i = 0; i < 4; ++i) {
                int c = c0 + 64 + sg * 8 + 2 * i;
                pre[i].x = xb[(size_t)c * 4096];
                pre[i].y = xb[(size_t)(c + 1) * 4096];
            }
        }
        __syncthreads();
        const unsigned int* xr = &xs[(16 * strip + l15) * 32];
        #pragma unroll
        for (int kc = 0; kc < 2; ++kc) {
            union { uint4 v; short8 s8; } af;
            af.v = *reinterpret_cast<const uint4*>(&xr[((4 * kc + q) ^ (l15 & 7)) << 2]);
            #pragma unroll
            for (int kt = 0; kt < 6; ++kt) {
                short8 bb = *reinterpret_cast<const short8*>(
                    &wqkv[(size_t)(ksel * 96 + kt * 16 + l15) * 512 + c0 + kc * 32 + q * 8]);
                acc[kt] = __builtin_amdgcn_mfma_f32_16x16x32_bf16(af.s8, bb, acc[kt], 0, 0, 0);
            }
        }
    }

    const int nloc = n0 + 16 * strip + 4 * q;
    if (ksel == 0) {
        #pragma unroll
        for (int kt = 0; kt < 4; ++kt) {       // Q (exp2-domain)
            int k = kt * 16 + l15;
            float bb = bfv[k];
            #pragma unroll
            for (int r = 0; r < 4; ++r)
                Qb[((size_t)b * 4096 + nloc + r) * 64 + k] = f2bf((acc[kt][r] + bb) * LOG2E);
        }
        #pragma unroll
        for (int kt = 4; kt < 6; ++kt) {       // K rows 0..31
            int k = (kt - 4) * 16 + l15;
            float bb = bgv[k];
            #pragma unroll
            for (int r = 0; r < 4; ++r)
                Kb[((size_t)b * 4096 + nloc + r) * 64 + k] = f2bf(acc[kt][r] + bb);
        }
    } else {
        #pragma unroll
        for (int kt = 0; kt < 2; ++kt) {       // K rows 32..63
            int k = 32 + kt * 16 + l15;
            float bb = bgv[k];
            #pragma unroll
            for (int r = 0; r < 4; ++r)
                Kb[((size_t)b * 4096 + nloc + r) * 64 + k] = f2bf(acc[kt][r] + bb);
        }
    }
    __syncthreads();
    if (ksel == 1) {                           // V -> LDS [d][n/2] (stride 17 dwords)
        #pragma unroll
        for (int kt = 2; kt < 6; ++kt) {
            int d = (kt - 2) * 16 + l15;
            float bb = bhv[d];
            int base = d * 17 + 8 * strip + 2 * q;
            xs[base]     = f2bf_pk(acc[kt][0] + bb, acc[kt][1] + bb);
            xs[base + 1] = f2bf_pk(acc[kt][2] + bb, acc[kt][3] + bb);
        }
    }
    __syncthreads();
    {   // coalesced store Vt[b][d][n0..n0+31]
        int d = tid >> 2, sgg = tid & 3;
        uint4 vv;
        vv.x = xs[d * 17 + sgg * 4 + 0]; vv.y = xs[d * 17 + sgg * 4 + 1];
        vv.z = xs[d * 17 + sgg * 4 + 2]; vv.w = xs[d * 17 + sgg * 4 + 3];
        *reinterpret_cast<uint4*>(&Vt[((size_t)b * 64 + d) * 4096 + n0 + sgg * 8]) = vv;
    }
}

// ---------------------------------------------------------------------------
// Flash attention, 32x32x16 MFMA, XOR-swizzled b128 LDS, v_exp_f32 softmax.
// launch_bounds(256,3): ~168 VGPR cap -> no spills (live set ~130), the R4/R5
// 80-VGPR allocation was spilling every loop iteration.
// ---------------------------------------------------------------------------
__global__ __launch_bounds__(256, 3) void attn_kernel(
    const ushortt* __restrict__ Qb, const ushortt* __restrict__ Kb,
    const ushortt* __restrict__ Vt, ushortt* __restrict__ Opart,
    float2* __restrict__ ml, ushortt* __restrict__ Ob, int KB) {
    __shared__ unsigned int smem[4420];
    const int tid = threadIdx.x;
    const int n0 = blockIdx.x * 64, b = blockIdx.y, s = blockIdx.z;
    const int lane = tid & 63, w = tid >> 6;
    const int qh = w & 1, kh = w >> 1;
    const int l31 = lane & 31, h = lane >> 5;

    const ushortt* Kg = Kb + (size_t)b * 4096 * 64;
    const ushortt* Vg = Vt + (size_t)b * 64 * 4096;

    short8 bq[4];
    {
        const ushortt* Qg = Qb + ((size_t)b * 4096 + n0 + 32 * qh + l31) * 64;
        #pragma unroll
        for (int kc = 0; kc < 4; ++kc)
            bq[kc] = *reinterpret_cast<const short8*>(Qg + kc * 16 + 8 * h);
    }

    floatx16 ot0 = {}, ot1 = {};
    float m_i = -1e30f, l_i = 0.f;

    const int row = tid >> 2, seg = tid & 3;
    const int kbeg = s * KB, kend = kbeg + KB;

    uint4 ck0, ck1, cv0, cv1;
    {
        int nb = kbeg * 64;
        const ushortt* kp = Kg + (size_t)(nb + row) * 64 + seg * 16;
        ck0 = *reinterpret_cast<const uint4*>(kp);
        ck1 = *reinterpret_cast<const uint4*>(kp + 8);
        const ushortt* vp = Vg + (size_t)row * 4096 + nb + seg * 16;
        cv0 = *reinterpret_cast<const uint4*>(vp);
        cv1 = *reinterpret_cast<const uint4*>(vp + 8);
    }

    const int rsw = row & 7;
    for (int kb = kbeg; kb < kend; ++kb) {
        __syncthreads();
        {
            *reinterpret_cast<uint4*>(&smem[row * 32 + (((2 * seg) ^ rsw) << 2)]) = ck0;
            *reinterpret_cast<uint4*>(&smem[row * 32 + (((2 * seg + 1) ^ rsw) << 2)]) = ck1;
            *reinterpret_cast<uint4*>(&smem[2048 + row * 32 + (((2 * seg) ^ rsw) << 2)]) = cv0;
            *reinterpret_cast<uint4*>(&smem[2048 + row * 32 + (((2 * seg + 1) ^ rsw) << 2)]) = cv1;
        }
        if (kb + 1 < kend) {
            int nb = (kb + 1) * 64;
            const ushortt* kp = Kg + (size_t)(nb + row) * 64 + seg * 16;
            ck0 = *reinterpret_cast<const uint4*>(kp);
            ck1 = *reinterpret_cast<const uint4*>(kp + 8);
            const ushortt* vp = Vg + (size_t)row * 4096 + nb + seg * 16;
            cv0 = *reinterpret_cast<const uint4*>(vp);
            cv1 = *reinterpret_cast<const uint4*>(vp + 8);
        }
        __syncthreads();

        floatx16 st = {};
        const unsigned int* kr = &smem[(32 * kh + l31) * 32];
        const int esw = l31 & 7;
        #pragma unroll
        for (int kc = 0; kc < 4; ++kc) {
            union { uint4 v; short8 s8; } af;
            af.v = *reinterpret_cast<const uint4*>(&kr[((2 * kc + h) ^ esw) << 2]);
            st = __builtin_amdgcn_mfma_f32_32x32x16_bf16(af.s8, bq[kc], st, 0, 0, 0);
        }

        float mx = st[0];
        #pragma unroll
        for (int r = 1; r < 16; ++r) mx = fmaxf(mx, st[r]);
        mx = fmaxf(mx, __shfl_xor(mx, 32));
        if (__any(mx > m_i)) {
            float mn = fmaxf(m_i, mx);
            float alpha = fast_exp2(m_i - mn);
            m_i = mn;
            l_i *= alpha;
            #pragma unroll
            for (int r = 0; r < 16; ++r) { ot0[r] *= alpha; ot1[r] *= alpha; }
        }
        float p[16], rs = 0.f;
        #pragma unroll
        for (int r = 0; r < 16; ++r) { p[r] = fast_exp2(st[r] - m_i); rs += p[r]; }
        rs += __shfl_xor(rs, 32);
        l_i += rs;

        unsigned int pk[8], sp[8];
        #pragma unroll
        for (int i = 0; i < 8; ++i) pk[i] = f2bf_pk(p[2 * i], p[2 * i + 1]);
        #pragma unroll
        for (int i = 0; i < 8; ++i) sp[i] = (unsigned int)__shfl_xor((int)pk[i], 32);
        union { unsigned int u[4]; short8 s8; } pb0, pb1;
        pb0.u[0] = h ? sp[2] : pk[0]; pb0.u[1] = h ? sp[3] : pk[1];
        pb0.u[2] = h ? pk[2] : sp[0]; pb0.u[3] = h ? pk[3] : sp[1];
        pb1.u[0] = h ? sp[6] : pk[4]; pb1.u[1] = h ? sp[7] : pk[5];
        pb1.u[2] = h ? pk[6] : sp[4]; pb1.u[3] = h ? pk[7] : sp[5];

        const unsigned int* vr0 = &smem[2048 + l31 * 32];
        const unsigned int* vr1 = &smem[2048 + (32 + l31) * 32];
        #pragma unroll
        for (int c = 0; c < 2; ++c) {
            union { uint4 v; short8 s8; } af;
            af.v = *reinterpret_cast<const uint4*>(&vr0[((4 * kh + 2 * c + h) ^ esw) << 2]);
            ot0 = __builtin_amdgcn_mfma_f32_32x32x16_bf16(af.s8, c ? pb1.s8 : pb0.s8, ot0, 0, 0, 0);
            af.v = *reinterpret_cast<const uint4*>(&vr1[((4 * kh + 2 * c + h) ^ esw) << 2]);
            ot1 = __builtin_amdgcn_mfma_f32_32x32x16_bf16(af.s8, c ? pb1.s8 : pb0.s8, ot1, 0, 0, 0);
        }
    }

    // ---- merge kh halves ----
    __syncthreads();
    if (h == 0) {
        smem[4160 + w * 32 + l31] = __float_as_uint(m_i);
        smem[4288 + w * 32 + l31] = __float_as_uint(l_i);
    }
    __syncthreads();
    int pw = 2 * (1 - kh) + qh;
    float m2 = __uint_as_float(smem[4160 + pw * 32 + l31]);
    float l2 = __uint_as_float(smem[4288 + pw * 32 + l31]);
    float mstar = fmaxf(m_i, m2);
    float wself = fast_exp2(m_i - mstar);
    float w2 = fast_exp2(m2 - mstar);
    float lm = wself * l_i + w2 * l2;
    float sc = (gridDim.z == 1) ? (wself / lm) : wself;
    if (gridDim.z > 1 && kh == 0 && h == 0) {
        float2 v; v.x = mstar; v.y = lm;
        ml[((size_t)s * 4 + b) * 4096 + n0 + 32 * qh + l31] = v;
    }
    float* om = reinterpret_cast<float*>(smem);
    if (kh == 0) {
        #pragma unroll
        for (int r = 0; r < 16; ++r) {
            int d0 = (r & 3) + 8 * (r >> 2) + 4 * h;
            om[(32 * qh + l31) * 65 + d0] = sc * ot0[r];
            om[(32 * qh + l31) * 65 + 32 + d0] = sc * ot1[r];
        }
    }
    __syncthreads();
    if (kh == 1) {
        #pragma unroll
        for (int r = 0; r < 16; ++r) {
            int d0 = (r & 3) + 8 * (r >> 2) + 4 * h;
            om[(32 * qh + l31) * 65 + d0] += sc * ot0[r];
            om[(32 * qh + l31) * 65 + 32 + d0] += sc * ot1[r];
        }
    }
    __syncthreads();
    {
        int qq = tid >> 2, dsg = tid & 3;
        unsigned int pkk[8];
        #pragma unroll
        for (int j = 0; j < 8; ++j)
            pkk[j] = f2bf_pk(om[qq * 65 + dsg * 16 + 2 * j], om[qq * 65 + dsg * 16 + 2 * j + 1]);
        ushortt* base = (gridDim.z == 1)
            ? (Ob + ((size_t)b * 4096 + n0) * 64)
            : (Opart + (((size_t)s * 4 + b) * 4096 + n0) * 64);
        uint4* d4 = reinterpret_cast<uint4*>(base + (size_t)qq * 64 + dsg * 16);
        uint4 o0; o0.x = pkk[0]; o0.y = pkk[1]; o0.z = pkk[2]; o0.w = pkk[3];
        uint4 o1; o1.x = pkk[4]; o1.y = pkk[5]; o1.z = pkk[6]; o1.w = pkk[7];
        d4[0] = o0; d4[1] = o1;
    }
}

// ---------------------------------------------------------------------------
// Merge KV-split partials (bf16 Opart, exp2-domain m).
// ---------------------------------------------------------------------------
__global__ __launch_bounds__(256) void combine_kernel(
    const ushortt* __restrict__ Opart, const float2* __restrict__ ml,
    ushortt* __restrict__ Ob, int S) {
    const int tid = threadIdx.x;
    const int n0 = blockIdx.x * 64, b = blockIdx.y;
    const int row = n0 + (tid >> 2), dseg = tid & 3;
    float2 mls[4];
    float m = -1e30f;
    for (int s = 0; s < S; ++s) {
        mls[s] = ml[((size_t)s * 4 + b) * 4096 + row];
        m = fmaxf(m, mls[s].x);
    }
    float wgt[4], denom = 0.f;
    for (int s = 0; s < S; ++s) {
        wgt[s] = fast_exp2(mls[s].x - m);
        denom += wgt[s] * mls[s].y;
    }
    float inv = 1.0f / denom;
    float acc[16];
    #pragma unroll
    for (int j = 0; j < 16; ++j) acc[j] = 0.f;
    for (int s = 0; s < S; ++s) {
        const uint4* op = reinterpret_cast<const uint4*>(
            Opart + (((size_t)s * 4 + b) * 4096 + row) * 64 + dseg * 16);
        union { uint4 v; ushortt hh[8]; } u0, u1;
        u0.v = op[0]; u1.v = op[1];
        float ww = wgt[s];
        #pragma unroll
        for (int j = 0; j < 8; ++j) {
            acc[j] += ww * bf2f(u0.hh[j]);
            acc[8 + j] += ww * bf2f(u1.hh[j]);
        }
    }
    union { uint4 u[2]; unsigned int ww[8]; } pkv;
    #pragma unroll
    for (int j = 0; j < 8; ++j) pkv.ww[j] = f2bf_pk(acc[2 * j] * inv, acc[2 * j + 1] * inv);
    uint4* dst = reinterpret_cast<uint4*>(Ob + ((size_t)b * 4096 + row) * 64 + dseg * 16);
    dst[0] = pkv.u[0]; dst[1] = pkv.u[1];
}

// ---------------------------------------------------------------------------
// out = gamma*(Wv_sn O + bv) + x
// ---------------------------------------------------------------------------
__global__ __launch_bounds__(256) void proj_kernel(
    const ushortt* __restrict__ Ob, const ushortt* __restrict__ wvb,
    const float* __restrict__ bv, const float* __restrict__ gamma,
    const float* __restrict__ x, float* __restrict__ out) {
    const int tid = threadIdx.x;
    const int n0 = blockIdx.y * 64, c0 = blockIdx.x * 64, b = blockIdx.z;
    const int w = tid >> 6, lane = tid & 63, q = lane >> 4, l15 = lane & 15;

    short8 a0 = *reinterpret_cast<const short8*>(&wvb[(size_t)(c0 + 16 * w + l15) * 64 + q * 8]);
    short8 a1 = *reinterpret_cast<const short8*>(&wvb[(size_t)(c0 + 16 * w + l15) * 64 + 32 + q * 8]);
    floatx4 acc[4];
    #pragma unroll
    for (int t = 0; t < 4; ++t) acc[t] = (floatx4){0.f, 0.f, 0.f, 0.f};
    #pragma unroll
    for (int t = 0; t < 4; ++t) {
        const ushortt* ob = Ob + ((size_t)b * 4096 + n0 + 16 * t + l15) * 64;
        short8 b0 = *reinterpret_cast<const short8*>(ob + q * 8);
        short8 b1 = *reinterpret_cast<const short8*>(ob + 32 + q * 8);
        acc[t] = __builtin_amdgcn_mfma_f32_16x16x32_bf16(a0, b0, acc[t], 0, 0, 0);
        acc[t] = __builtin_amdgcn_mfma_f32_16x16x32_bf16(a1, b1, acc[t], 0, 0, 0);
    }
    float gm = gamma[0];
    #pragma unroll
    for (int t = 0; t < 4; ++t) {
        #pragma unroll
        for (int r = 0; r < 4; ++r) {
            int c = c0 + 16 * w + 4 * q + r;
            int n = n0 + 16 * t + l15;
            size_t idx = ((size_t)(b * 512 + c)) * 4096 + n;
            out[idx] = gm * (acc[t][r] + bv[c]) + x[idx];
        }
    }
}

// ---------------------------------------------------------------------------
extern "C" void kernel_launch(void* const* d_in, const int* in_sizes, int n_in,
                              void* d_out, int out_size, void* d_ws, size_t ws_size,
                              hipStream_t stream) {
    const float* x   = (const float*)d_in[0];
    const float* Wf  = (const float*)d_in[1];
    const float* bf_ = (const float*)d_in[2];
    const float* Wg  = (const float*)d_in[3];
    const float* bg_ = (const float*)d_in[4];
    const float* Wh  = (const float*)d_in[5];
    const float* bh_ = (const float*)d_in[6];
    const float* Wv  = (const float*)d_in[7];
    const float* bv_ = (const float*)d_in[8];
    const float* uf  = (const float*)d_in[9];
    const float* ug  = (const float*)d_in[10];
    const float* uh  = (const float*)d_in[11];
    const float* uv  = (const float*)d_in[12];
    const float* gm  = (const float*)d_in[13];
    float* out = (float*)d_out;

    char* ws = (char*)d_ws;
    float*   sig   = (float*)ws;                         // 256 B
    ushortt* wqkv  = (ushortt*)(ws + 256);               // 196608
    ushortt* wvb   = (ushortt*)(ws + 196864);            // 65536
    ushortt* Qb    = (ushortt*)(ws + 262400);            // 2 MB
    ushortt* Kb    = (ushortt*)(ws + 2359552);           // 2 MB
    ushortt* Vt    = (ushortt*)(ws + 4456704);           // 2 MB  [b][d][n]
    ushortt* Ob    = (ushortt*)(ws + 6553856);           // 2 MB
    float2*  ml    = (float2*)(ws + 8651008);            // 512 KB (S=4)
    ushortt* Opart = (ushortt*)(ws + 9175296);           // 8 MB bf16 (S=4)

    int S = (ws_size >= (size_t)17563904) ? 4 : 1;

    sigma_kernel<<<4, 256, 0, stream>>>(Wf, uf, Wg, ug, Wh, uh, Wv, uv, sig);
    prep_w_kernel<<<512, 256, 0, stream>>>(Wf, Wg, Wh, Wv, sig, wqkv, wvb);
    qkv_kernel<<<dim3(128, 4), 256, 0, stream>>>(x, wqkv, bf_, bg_, bh_, Qb, Kb, Vt);
    attn_kernel<<<dim3(64, 4, S), 256, 0, stream>>>(Qb, Kb, Vt, Opart, ml, Ob, 64 / S);
    if (S > 1) combine_kernel<<<dim3(64, 4), 256, 0, stream>>>(Opart, ml, Ob, S);
    proj_kernel<<<dim3(8, 64, 4), 256, 0, stream>>>(Ob, wvb, bv_, gm, x, out);
}